// Round 5
// baseline (148.942 us; speedup 1.0000x reference)
//
#include <hip/hip_runtime.h>
#include <math.h>

#define BATCH  8
#define SEQ    8192
#define DMODEL 256
#define DSTATE 2
#define CHUNKS 256   // C
#define CLEN   32    // L = SEQ / C
#define CPAD   1040  // floats per (b,c) E row: 1024 data + 16 pad (4160 B stride)
#define NSEG   16    // segments per batch-scan
#define SEGLEN 16    // chunks per segment = CHUNKS / NSEG
#define GROW   1040  // floats per (b,seg) G row: 1024 data + 16 pad

// ---------------------------------------------------------------------------
// Round 5: fix the round-4 regression. K3's lookback loops had runtime trip
// counts (seg, i) -> serial load-use chains at L2 latency (~2.7 us tail).
// Now: fixed-trip grouped loads (4 unconditional row loads per group, always
// valid addresses) + predicated folds. K1 unroll 16; K2 float4-widened.
// Pipeline: K1 (x -> E), K2 (E -> G), K3 (x,E,G -> y). 3 dispatches.
//   K1/K3: 2048 blocks x 256 threads, block = chunk (b,c), thread = channel d
//   -> 8192 waves = 32 waves/CU (round-3 TLP fix, kept; VGPR <= 64).
// Layouts:
//   x, y : [B][T][D] fp32
//   E: [B][C][CPAD] floats; thread d owns float4 {s0re,s0im,s1re,s1im} at d*4.
//   G: [B][NSEG][GROW] floats, same slot layout.
// Recurrence: h[t] = a h[t-1] + B x[t], a = e^{lm}(cos ph + i sin ph)
// y[t,d] = sum_s Re(C h) + D_diag x
// ---------------------------------------------------------------------------

// Kernel 1: per-chunk local end state (zero init).
__global__ __launch_bounds__(256, 8)
void ssm_chunk_state(const float* __restrict__ x,
                     const float* __restrict__ lam,
                     const float* __restrict__ aph,
                     const float* __restrict__ Bre,
                     const float* __restrict__ Bim,
                     float* __restrict__ E) {
    const int d   = threadIdx.x;
    const int bid = blockIdx.x;
    const int b   = bid >> 8;
    const int c   = bid & (CHUNKS - 1);

    const float2 lm2 = *reinterpret_cast<const float2*>(lam + d * 2);
    const float2 ph2 = *reinterpret_cast<const float2*>(aph + d * 2);
    const float2 br2 = *reinterpret_cast<const float2*>(Bre + d * 2);
    const float2 bi2 = *reinterpret_cast<const float2*>(Bim + d * 2);
    const float m0 = expf(lm2.x), m1 = expf(lm2.y);
    const float ar0 = m0 * cosf(ph2.x), ai0 = m0 * sinf(ph2.x);
    const float ar1 = m1 * cosf(ph2.y), ai1 = m1 * sinf(ph2.y);
    const float br0 = br2.x, br1 = br2.y, bi0 = bi2.x, bi1 = bi2.y;

    float hr0 = 0.f, hi0 = 0.f, hr1 = 0.f, hi1 = 0.f;
    const float* xp = x + ((size_t)b * SEQ + (size_t)c * CLEN) * DMODEL + d;
#pragma unroll 16
    for (int t = 0; t < CLEN; ++t) {
        const float xt = xp[(size_t)t * DMODEL];
        const float n0r = fmaf(ar0, hr0, fmaf(-ai0, hi0, br0 * xt));
        const float n0i = fmaf(ar0, hi0, fmaf( ai0, hr0, bi0 * xt));
        const float n1r = fmaf(ar1, hr1, fmaf(-ai1, hi1, br1 * xt));
        const float n1i = fmaf(ar1, hi1, fmaf( ai1, hr1, bi1 * xt));
        hr0 = n0r; hi0 = n0i; hr1 = n1r; hi1 = n1i;
    }

    float4 ev;
    ev.x = hr0; ev.y = hi0; ev.z = hr1; ev.w = hi1;
    *reinterpret_cast<float4*>(E + ((size_t)b * CHUNKS + c) * CPAD + d * 4) = ev;
}

// Kernel 2: segment aggregates (E -> G), float4 per thread (both states).
// 128 blocks (b, seg) x 256 threads; thread owns channel d; all 16 chunk rows
// preloaded (fixed trip -> parallel loads), then 15 Horner folds.
__global__ __launch_bounds__(256, 4)
void ssm_seg_aggregate(const float* __restrict__ E,
                       const float* __restrict__ lam,
                       const float* __restrict__ aph,
                       float* __restrict__ G) {
    const int bid = blockIdx.x;
    const int b   = bid >> 4;
    const int seg = bid & (NSEG - 1);
    const int d   = threadIdx.x;

    const float2 lm2 = *reinterpret_cast<const float2*>(lam + d * 2);
    const float2 ph2 = *reinterpret_cast<const float2*>(aph + d * 2);
    // A_L = a^CLEN via fp64 squarings (no libm): a from fp32 params.
    const float m0 = expf(lm2.x), m1 = expf(lm2.y);
    double w0r = (double)(m0 * cosf(ph2.x)), w0i = (double)(m0 * sinf(ph2.x));
    double w1r = (double)(m1 * cosf(ph2.y)), w1i = (double)(m1 * sinf(ph2.y));
#pragma unroll
    for (int q = 0; q < 5; ++q) {   // a^32
        double t0 = w0r * w0r - w0i * w0i; w0i = 2.0 * w0r * w0i; w0r = t0;
        double t1 = w1r * w1r - w1i * w1i; w1i = 2.0 * w1r * w1i; w1r = t1;
    }
    const float A0r = (float)w0r, A0i = (float)w0i;
    const float A1r = (float)w1r, A1i = (float)w1i;

    const float* ep =
        E + ((size_t)b * CHUNKS + (size_t)seg * SEGLEN) * CPAD + d * 4;

    float4 e[SEGLEN];
#pragma unroll
    for (int i = 0; i < SEGLEN; ++i)
        e[i] = *reinterpret_cast<const float4*>(ep + (size_t)i * CPAD);

    float v0r = e[0].x, v0i = e[0].y, v1r = e[0].z, v1i = e[0].w;
#pragma unroll
    for (int i = 1; i < SEGLEN; ++i) {
        const float n0r = fmaf(A0r, v0r, fmaf(-A0i, v0i, e[i].x));
        const float n0i = fmaf(A0r, v0i, fmaf( A0i, v0r, e[i].y));
        const float n1r = fmaf(A1r, v1r, fmaf(-A1i, v1i, e[i].z));
        const float n1i = fmaf(A1r, v1i, fmaf( A1i, v1r, e[i].w));
        v0r = n0r; v0i = n0i; v1r = n1r; v1i = n1i;
    }

    float4 gv;
    gv.x = v0r; gv.y = v0i; gv.z = v1r; gv.w = v1i;
    *reinterpret_cast<float4*>(G + ((size_t)b * NSEG + seg) * GROW + d * 4) = gv;
}

// Kernel 3: lookback prefix (grouped fixed-trip folds) + replay + output.
__global__ __launch_bounds__(256, 8)
void ssm_output(const float* __restrict__ x,
                const float* __restrict__ lam,
                const float* __restrict__ aph,
                const float* __restrict__ Bre,
                const float* __restrict__ Bim,
                const float* __restrict__ Cre,
                const float* __restrict__ Cim,
                const float* __restrict__ Dd,
                const float* __restrict__ E,
                const float* __restrict__ G,
                float* __restrict__ y) {
    const int d   = threadIdx.x;
    const int bid = blockIdx.x;
    const int b   = bid >> 8;
    const int c   = bid & (CHUNKS - 1);
    const int seg = c >> 4;          // SEGLEN = 16
    const int i   = c & (SEGLEN - 1);

    const float2 lm2 = *reinterpret_cast<const float2*>(lam + d * 2);
    const float2 ph2 = *reinterpret_cast<const float2*>(aph + d * 2);
    const float2 br2 = *reinterpret_cast<const float2*>(Bre + d * 2);
    const float2 bi2 = *reinterpret_cast<const float2*>(Bim + d * 2);
    const float2 cr2 = *reinterpret_cast<const float2*>(Cre + d * 2);
    const float2 ci2 = *reinterpret_cast<const float2*>(Cim + d * 2);
    const float dd  = Dd[d];
    const float m0 = expf(lm2.x), m1 = expf(lm2.y);
    const float ar0 = m0 * cosf(ph2.x), ai0 = m0 * sinf(ph2.x);
    const float ar1 = m1 * cosf(ph2.y), ai1 = m1 * sinf(ph2.y);
    const float br0 = br2.x, br1 = br2.y, bi0 = bi2.x, bi1 = bi2.y;
    const float cr0 = cr2.x, cr1 = cr2.y, ci0 = ci2.x, ci1 = ci2.y;

    // A_L = a^32 (5 squarings), A_seg = A_L^16 (4 more) — fp64 mul/add only.
    double w0r = (double)ar0, w0i = (double)ai0;
    double w1r = (double)ar1, w1i = (double)ai1;
#pragma unroll
    for (int q = 0; q < 5; ++q) {
        double t0 = w0r * w0r - w0i * w0i; w0i = 2.0 * w0r * w0i; w0r = t0;
        double t1 = w1r * w1r - w1i * w1i; w1i = 2.0 * w1r * w1i; w1r = t1;
    }
    const float AL0r = (float)w0r, AL0i = (float)w0i;
    const float AL1r = (float)w1r, AL1i = (float)w1i;
#pragma unroll
    for (int q = 0; q < 4; ++q) {
        double t0 = w0r * w0r - w0i * w0i; w0i = 2.0 * w0r * w0i; w0r = t0;
        double t1 = w1r * w1r - w1i * w1i; w1i = 2.0 * w1r * w1i; w1r = t1;
    }
    const float AS0r = (float)w0r, AS0i = (float)w0i;
    const float AS1r = (float)w1r, AS1i = (float)w1i;

    // segment prefix from G: P = sum_{k<seg} A_seg^(seg-1-k) G[k]
    // Grouped fixed-trip: 4 unconditional loads (rows always valid) +
    // predicated folds. Outer loop kept rolled (unroll 1) to bound VGPRs.
    float P0r = 0.f, P0i = 0.f, P1r = 0.f, P1i = 0.f;
    const float* gp = G + (size_t)b * NSEG * GROW + d * 4;
#pragma unroll 1
    for (int k0 = 0; k0 < NSEG; k0 += 4) {
        float4 g0 = *reinterpret_cast<const float4*>(gp + (size_t)(k0 + 0) * GROW);
        float4 g1 = *reinterpret_cast<const float4*>(gp + (size_t)(k0 + 1) * GROW);
        float4 g2 = *reinterpret_cast<const float4*>(gp + (size_t)(k0 + 2) * GROW);
        float4 g3 = *reinterpret_cast<const float4*>(gp + (size_t)(k0 + 3) * GROW);
#pragma unroll
        for (int u = 0; u < 4; ++u) {
            const float4 gv = (u == 0) ? g0 : (u == 1) ? g1 : (u == 2) ? g2 : g3;
            if (k0 + u < seg) {
                const float n0r = fmaf(AS0r, P0r, fmaf(-AS0i, P0i, gv.x));
                const float n0i = fmaf(AS0r, P0i, fmaf( AS0i, P0r, gv.y));
                const float n1r = fmaf(AS1r, P1r, fmaf(-AS1i, P1i, gv.z));
                const float n1i = fmaf(AS1r, P1i, fmaf( AS1i, P1r, gv.w));
                P0r = n0r; P0i = n0i; P1r = n1r; P1i = n1i;
            }
        }
    }
    // within-segment fold from E: P = A_L*P + E[seg*16+j], j<i  (same trick)
    const float* ep =
        E + ((size_t)b * CHUNKS + (size_t)seg * SEGLEN) * CPAD + d * 4;
#pragma unroll 1
    for (int j0 = 0; j0 < SEGLEN; j0 += 4) {
        float4 e0 = *reinterpret_cast<const float4*>(ep + (size_t)(j0 + 0) * CPAD);
        float4 e1 = *reinterpret_cast<const float4*>(ep + (size_t)(j0 + 1) * CPAD);
        float4 e2 = *reinterpret_cast<const float4*>(ep + (size_t)(j0 + 2) * CPAD);
        float4 e3 = *reinterpret_cast<const float4*>(ep + (size_t)(j0 + 3) * CPAD);
#pragma unroll
        for (int u = 0; u < 4; ++u) {
            const float4 ev = (u == 0) ? e0 : (u == 1) ? e1 : (u == 2) ? e2 : e3;
            if (j0 + u < i) {
                const float n0r = fmaf(AL0r, P0r, fmaf(-AL0i, P0i, ev.x));
                const float n0i = fmaf(AL0r, P0i, fmaf( AL0i, P0r, ev.y));
                const float n1r = fmaf(AL1r, P1r, fmaf(-AL1i, P1i, ev.z));
                const float n1i = fmaf(AL1r, P1i, fmaf( AL1i, P1r, ev.w));
                P0r = n0r; P0i = n0i; P1r = n1r; P1i = n1i;
            }
        }
    }

    float hr0 = P0r, hi0 = P0i, hr1 = P1r, hi1 = P1i;

    const size_t tbase = ((size_t)b * SEQ + (size_t)c * CLEN) * DMODEL + d;
    const float* xp = x + tbase;
    float* yp = y + tbase;
#pragma unroll 8
    for (int t = 0; t < CLEN; ++t) {
        const float xt = xp[(size_t)t * DMODEL];
        const float n0r = fmaf(ar0, hr0, fmaf(-ai0, hi0, br0 * xt));
        const float n0i = fmaf(ar0, hi0, fmaf( ai0, hr0, bi0 * xt));
        const float n1r = fmaf(ar1, hr1, fmaf(-ai1, hi1, br1 * xt));
        const float n1i = fmaf(ar1, hi1, fmaf( ai1, hr1, bi1 * xt));
        hr0 = n0r; hi0 = n0i; hr1 = n1r; hi1 = n1i;
        float acc = dd * xt;
        acc = fmaf(cr0, n0r, acc);
        acc = fmaf(-ci0, n0i, acc);
        acc = fmaf(cr1, n1r, acc);
        acc = fmaf(-ci1, n1i, acc);
        // y is never re-read: nontemporal store keeps x L3-resident.
        __builtin_nontemporal_store(acc, yp + (size_t)t * DMODEL);
    }
}

extern "C" void kernel_launch(void* const* d_in, const int* in_sizes, int n_in,
                              void* d_out, int out_size, void* d_ws, size_t ws_size,
                              hipStream_t stream) {
    const float* x   = (const float*)d_in[0];
    const float* lam = (const float*)d_in[1];
    const float* aph = (const float*)d_in[2];
    const float* Bre = (const float*)d_in[3];
    const float* Bim = (const float*)d_in[4];
    const float* Cre = (const float*)d_in[5];
    const float* Cim = (const float*)d_in[6];
    const float* Dd  = (const float*)d_in[7];
    float* yo = (float*)d_out;

    float* E = (float*)d_ws;                                      // ~8.5 MB
    float* G = E + (size_t)BATCH * CHUNKS * CPAD;                 // ~532 KB

    ssm_chunk_state<<<BATCH * CHUNKS, 256, 0, stream>>>(x, lam, aph, Bre, Bim, E);
    ssm_seg_aggregate<<<BATCH * NSEG, 256, 0, stream>>>(E, lam, aph, G);
    ssm_output<<<BATCH * CHUNKS, 256, 0, stream>>>(x, lam, aph, Bre, Bim,
                                                   Cre, Cim, Dd, E, G, yo);
}

// Round 6
// 146.754 us; speedup vs baseline: 1.0149x; 1.0149x over previous
//
#include <hip/hip_runtime.h>
#include <math.h>

#define BATCH  8
#define SEQ    8192
#define DMODEL 256
#define DSTATE 2
#define CHUNKS 256   // C
#define CLEN   32    // L = SEQ / C
#define CPAD   1040  // floats per (b,c) row: 1024 data + 16 pad (4160 B stride)
#define NSEG   16    // segments per batch-scan
#define SEGLEN 16    // chunks per segment = CHUNKS / NSEG

// ---------------------------------------------------------------------------
// Round 6: revert to the round-3 structure (best measured: 145.2 us).
// Rounds 4/5 proved in-K3 lookback costs +3.5 us vs streaming Hin: the Hin
// round-trip (~17 MB L2/L3-hot, pipelined) is cheaper than a serial lookback
// prologue + ~260 MB of redundant G/E re-reads across blocks.
// Pipeline: K1 (x->E), K2a (E->G), K2b (E,G->Hin), K3 (x,Hin->y).
//   K1/K3: 2048 blocks x 256 threads, block = chunk (b,c), thread = channel d
//   -> 8192 waves = 32 waves/CU (round-3 TLP fix; VGPR <= 64).
// Layouts:
//   x, y : [B][T][D] fp32
//   E / Hin: [B][C][CPAD] floats; thread d owns float4 {s0re,s0im,s1re,s1im}
//     at float-offset d*4; scan slot r = d*2+s -> float2 at offset 2r.
//   G: [B][NSEG][512] float2 segment aggregates (512 KB)
// Recurrence: h[t] = a h[t-1] + B x[t], a = e^{lm}(cos ph + i sin ph)
// y[t,d] = sum_s Re(C h) + D_diag x
// ---------------------------------------------------------------------------

// Kernel 1: per-chunk local end state (zero init). unroll 16: more x-loads
// in flight per wave (carried from round 5, measured-safe at <=64 VGPR).
__global__ __launch_bounds__(256, 8)
void ssm_chunk_state(const float* __restrict__ x,
                     const float* __restrict__ lam,
                     const float* __restrict__ aph,
                     const float* __restrict__ Bre,
                     const float* __restrict__ Bim,
                     float* __restrict__ E) {
    const int d   = threadIdx.x;
    const int bid = blockIdx.x;
    const int b   = bid >> 8;
    const int c   = bid & (CHUNKS - 1);

    const float2 lm2 = *reinterpret_cast<const float2*>(lam + d * 2);
    const float2 ph2 = *reinterpret_cast<const float2*>(aph + d * 2);
    const float2 br2 = *reinterpret_cast<const float2*>(Bre + d * 2);
    const float2 bi2 = *reinterpret_cast<const float2*>(Bim + d * 2);
    const float m0 = expf(lm2.x), m1 = expf(lm2.y);
    const float ar0 = m0 * cosf(ph2.x), ai0 = m0 * sinf(ph2.x);
    const float ar1 = m1 * cosf(ph2.y), ai1 = m1 * sinf(ph2.y);
    const float br0 = br2.x, br1 = br2.y, bi0 = bi2.x, bi1 = bi2.y;

    float hr0 = 0.f, hi0 = 0.f, hr1 = 0.f, hi1 = 0.f;
    const float* xp = x + ((size_t)b * SEQ + (size_t)c * CLEN) * DMODEL + d;
#pragma unroll 16
    for (int t = 0; t < CLEN; ++t) {
        const float xt = xp[(size_t)t * DMODEL];
        const float n0r = fmaf(ar0, hr0, fmaf(-ai0, hi0, br0 * xt));
        const float n0i = fmaf(ar0, hi0, fmaf( ai0, hr0, bi0 * xt));
        const float n1r = fmaf(ar1, hr1, fmaf(-ai1, hi1, br1 * xt));
        const float n1i = fmaf(ar1, hi1, fmaf( ai1, hr1, bi1 * xt));
        hr0 = n0r; hi0 = n0i; hr1 = n1r; hi1 = n1i;
    }

    float4 ev;
    ev.x = hr0; ev.y = hi0; ev.z = hr1; ev.w = hi1;
    *reinterpret_cast<float4*>(E + ((size_t)b * CHUNKS + c) * CPAD + d * 4) = ev;
}

// Kernel 2a: segment aggregates, fully coalesced.
// 256 blocks (b, seg, half) x 256 threads; thread owns scan slot
// r = half*256+tid, serially folds its segment's 16 chunk states.
// G[b][seg][r] = sum_i A_L^(SEGLEN-1-i) e[seg*SEGLEN+i].
__global__ __launch_bounds__(256, 4)
void ssm_seg_aggregate(const float* __restrict__ E,
                       const float* __restrict__ lam,
                       const float* __restrict__ aph,
                       float* __restrict__ G) {
    const int bid  = blockIdx.x;
    const int b    = bid >> 5;
    const int seg  = (bid >> 1) & (NSEG - 1);
    const int r    = ((bid & 1) << 8) + threadIdx.x;
    const int d    = r >> 1;
    const int s    = r & 1;

    const double lm = (double)lam[d * 2 + s];
    const double ph = (double)aph[d * 2 + s];
    const double mL = exp(lm * (double)CLEN);
    const double pL = ph * (double)CLEN;
    const float Ar = (float)(mL * cos(pL));   // A_L = a^CLEN
    const float Ai = (float)(mL * sin(pL));

    const size_t ebase =
        ((size_t)b * CHUNKS + (size_t)seg * SEGLEN) * CPAD + (size_t)r * 2;

    float2 e[SEGLEN];
#pragma unroll
    for (int i = 0; i < SEGLEN; ++i)
        e[i] = *reinterpret_cast<const float2*>(E + ebase + (size_t)i * CPAD);

    float vr = e[0].x, vi = e[0].y;
#pragma unroll
    for (int i = 1; i < SEGLEN; ++i) {
        const float nr = fmaf(Ar, vr, fmaf(-Ai, vi, e[i].x));
        const float ni = fmaf(Ar, vi, fmaf( Ai, vr, e[i].y));
        vr = nr; vi = ni;
    }

    *reinterpret_cast<float2*>(G + (((size_t)b * NSEG + seg) * 512 + r) * 2) =
        make_float2(vr, vi);
}

// Kernel 2b: fold segment-prefix from G (fixed-trip predicated), replay
// segment writing exclusive per-chunk prefixes to Hin. Same coalescing as 2a.
// S_seg = sum_{k<seg} A_seg^(seg-1-k) G[k], A_seg = a^(CLEN*SEGLEN).
__global__ __launch_bounds__(256, 4)
void ssm_seg_scan(const float* __restrict__ E,
                  const float* __restrict__ G,
                  const float* __restrict__ lam,
                  const float* __restrict__ aph,
                  float* __restrict__ Hin) {
    const int bid  = blockIdx.x;
    const int b    = bid >> 5;
    const int seg  = (bid >> 1) & (NSEG - 1);
    const int r    = ((bid & 1) << 8) + threadIdx.x;
    const int d    = r >> 1;
    const int s    = r & 1;

    const double lm = (double)lam[d * 2 + s];
    const double ph = (double)aph[d * 2 + s];
    const double mL = exp(lm * (double)CLEN);
    const double pL = ph * (double)CLEN;
    const float Ar = (float)(mL * cos(pL));                    // A_L
    const float Ai = (float)(mL * sin(pL));
    const double mS = exp(lm * (double)(CLEN * SEGLEN));
    const double pS = ph * (double)(CLEN * SEGLEN);
    const float Sr = (float)(mS * cos(pS));                    // A_seg
    const float Si = (float)(mS * sin(pS));

    float2 g[NSEG];
#pragma unroll
    for (int k = 0; k < NSEG; ++k)
        g[k] = *reinterpret_cast<const float2*>(
            G + (((size_t)b * NSEG + k) * 512 + r) * 2);

    const size_t ebase =
        ((size_t)b * CHUNKS + (size_t)seg * SEGLEN) * CPAD + (size_t)r * 2;
    float2 e[SEGLEN];
#pragma unroll
    for (int i = 0; i < SEGLEN; ++i)
        e[i] = *reinterpret_cast<const float2*>(E + ebase + (size_t)i * CPAD);

    float pr = 0.f, pi = 0.f;
#pragma unroll
    for (int k = 0; k < NSEG; ++k) {
        if (k < seg) {   // seg is block-uniform -> non-divergent
            const float nr = fmaf(Sr, pr, fmaf(-Si, pi, g[k].x));
            const float ni = fmaf(Sr, pi, fmaf( Si, pr, g[k].y));
            pr = nr; pi = ni;
        }
    }

#pragma unroll
    for (int i = 0; i < SEGLEN; ++i) {
        *reinterpret_cast<float2*>(Hin + ebase + (size_t)i * CPAD) =
            make_float2(pr, pi);
        const float nr = fmaf(Ar, pr, fmaf(-Ai, pi, e[i].x));
        const float ni = fmaf(Ar, pi, fmaf( Ai, pr, e[i].y));
        pr = nr; pi = ni;
    }
}

// Kernel 3: replay local recurrence seeded from Hin; fuse output projection.
// Hin load issued first so its latency hides under the param prologue.
__global__ __launch_bounds__(256, 8)
void ssm_output(const float* __restrict__ x,
                const float* __restrict__ lam,
                const float* __restrict__ aph,
                const float* __restrict__ Bre,
                const float* __restrict__ Bim,
                const float* __restrict__ Cre,
                const float* __restrict__ Cim,
                const float* __restrict__ Dd,
                const float* __restrict__ Hin,
                float* __restrict__ y) {
    const int d   = threadIdx.x;
    const int bid = blockIdx.x;
    const int b   = bid >> 8;
    const int c   = bid & (CHUNKS - 1);

    const float4 hv = *reinterpret_cast<const float4*>(
        Hin + ((size_t)b * CHUNKS + c) * CPAD + d * 4);
    float hr0 = hv.x, hi0 = hv.y, hr1 = hv.z, hi1 = hv.w;

    const float2 lm2 = *reinterpret_cast<const float2*>(lam + d * 2);
    const float2 ph2 = *reinterpret_cast<const float2*>(aph + d * 2);
    const float2 br2 = *reinterpret_cast<const float2*>(Bre + d * 2);
    const float2 bi2 = *reinterpret_cast<const float2*>(Bim + d * 2);
    const float2 cr2 = *reinterpret_cast<const float2*>(Cre + d * 2);
    const float2 ci2 = *reinterpret_cast<const float2*>(Cim + d * 2);
    const float dd  = Dd[d];
    const float m0 = expf(lm2.x), m1 = expf(lm2.y);
    const float ar0 = m0 * cosf(ph2.x), ai0 = m0 * sinf(ph2.x);
    const float ar1 = m1 * cosf(ph2.y), ai1 = m1 * sinf(ph2.y);
    const float br0 = br2.x, br1 = br2.y, bi0 = bi2.x, bi1 = bi2.y;
    const float cr0 = cr2.x, cr1 = cr2.y, ci0 = ci2.x, ci1 = ci2.y;

    const size_t tbase = ((size_t)b * SEQ + (size_t)c * CLEN) * DMODEL + d;
    const float* xp = x + tbase;
    float* yp = y + tbase;
#pragma unroll 8
    for (int t = 0; t < CLEN; ++t) {
        const float xt = xp[(size_t)t * DMODEL];
        const float n0r = fmaf(ar0, hr0, fmaf(-ai0, hi0, br0 * xt));
        const float n0i = fmaf(ar0, hi0, fmaf( ai0, hr0, bi0 * xt));
        const float n1r = fmaf(ar1, hr1, fmaf(-ai1, hi1, br1 * xt));
        const float n1i = fmaf(ar1, hi1, fmaf( ai1, hr1, bi1 * xt));
        hr0 = n0r; hi0 = n0i; hr1 = n1r; hi1 = n1i;
        float acc = dd * xt;
        acc = fmaf(cr0, n0r, acc);
        acc = fmaf(-ci0, n0i, acc);
        acc = fmaf(cr1, n1r, acc);
        acc = fmaf(-ci1, n1i, acc);
        // y is never re-read: nontemporal store keeps x L3-resident.
        __builtin_nontemporal_store(acc, yp + (size_t)t * DMODEL);
    }
}

extern "C" void kernel_launch(void* const* d_in, const int* in_sizes, int n_in,
                              void* d_out, int out_size, void* d_ws, size_t ws_size,
                              hipStream_t stream) {
    const float* x   = (const float*)d_in[0];
    const float* lam = (const float*)d_in[1];
    const float* aph = (const float*)d_in[2];
    const float* Bre = (const float*)d_in[3];
    const float* Bim = (const float*)d_in[4];
    const float* Cre = (const float*)d_in[5];
    const float* Cim = (const float*)d_in[6];
    const float* Dd  = (const float*)d_in[7];
    float* yo = (float*)d_out;

    float* E   = (float*)d_ws;                                    // ~8.5 MB
    float* Hin = E + (size_t)BATCH * CHUNKS * CPAD;               // ~8.5 MB
    float* G   = Hin + (size_t)BATCH * CHUNKS * CPAD;             // 512 KB

    ssm_chunk_state<<<BATCH * CHUNKS, 256, 0, stream>>>(x, lam, aph, Bre, Bim, E);
    ssm_seg_aggregate<<<BATCH * NSEG * 2, 256, 0, stream>>>(E, lam, aph, G);
    ssm_seg_scan<<<BATCH * NSEG * 2, 256, 0, stream>>>(E, G, lam, aph, Hin);
    ssm_output<<<BATCH * CHUNKS, 256, 0, stream>>>(x, lam, aph, Bre, Bim,
                                                   Cre, Cim, Dd, Hin, yo);
}